// Round 1
// baseline (343.112 us; speedup 1.0000x reference)
//
#include <hip/hip_runtime.h>
#include <cstdint>
#include <cstddef>

typedef __attribute__((ext_vector_type(8))) short s16x8;   // 8 x bf16 bits
typedef __attribute__((ext_vector_type(4))) float fx4;     // MFMA accumulator

#define AS1 __attribute__((address_space(1)))
#define AS3 __attribute__((address_space(3)))

__device__ __forceinline__ unsigned short f2bf(float f) {
    union { float f; unsigned u; } c; c.f = f;
    unsigned lsb = (c.u >> 16) & 1u;
    unsigned r = c.u + 0x7fffu + lsb;
    return (unsigned short)(r >> 16);
}
__device__ __forceinline__ float bf2f(unsigned short h) {
    union { unsigned u; float f; } c; c.u = ((unsigned)h) << 16;
    return c.f;
}

// ---------------- conversion kernels ----------------
// fp32 -> bf16, 4 elems/thread
__global__ __launch_bounds__(256) void conv4(const float* __restrict__ src,
                                             unsigned short* __restrict__ dst, int n4) {
    int i = blockIdx.x * 256 + threadIdx.x;
    if (i >= n4) return;
    float4 v = reinterpret_cast<const float4*>(src)[i];
    ushort4 o;
    o.x = f2bf(v.x); o.y = f2bf(v.y); o.z = f2bf(v.z); o.w = f2bf(v.w);
    reinterpret_cast<ushort4*>(dst)[i] = o;
}

// W [K x N] fp32 -> WT [N x K] bf16
__global__ __launch_bounds__(256) void convT(const float* __restrict__ W,
                                             unsigned short* __restrict__ WT, int K, int N) {
    int i = blockIdx.x * 256 + threadIdx.x;
    if (i >= N * K) return;
    int n = i / K, k = i - n * K;
    WT[i] = f2bf(W[(size_t)k * N + n]);
}

// ---------------- fused GEMM ----------------
// C[m][n] = ReLU( sum_k A[m][k]*W[k][n] + bias[n] ) stored bf16.
// MODE 0: A = Abase [M x K] bf16 contiguous.
// MODE 1: A row = concat(emb[idx[r*2+0]], emb[idx[r*2+1]], gvec)        (K=768)
// MODE 2: A row = concat(emb[idx[r*3+0..2]], gvec)                      (K=1024)
// WT is [N x K] bf16. Tile 128x128, BK=64, 4 waves (2x2 of 64x64).
__device__ __forceinline__ void compute64(const char* As, const char* Bs,
                                          fx4 (&acc)[4][4], int lane, int wm, int wn) {
#pragma unroll
    for (int kc = 0; kc < 2; ++kc) {
        s16x8 af[4], bf[4];
        int cb0 = kc * 64 + ((lane >> 4) << 4);
#pragma unroll
        for (int mi = 0; mi < 4; ++mi) {
            int row = wm * 64 + mi * 16 + (lane & 15);
            int cb = cb0 ^ ((row & 7) << 4);
            af[mi] = *reinterpret_cast<const s16x8*>(As + row * 128 + cb);
        }
#pragma unroll
        for (int ni = 0; ni < 4; ++ni) {
            int row = wn * 64 + ni * 16 + (lane & 15);
            int cb = cb0 ^ ((row & 7) << 4);
            bf[ni] = *reinterpret_cast<const s16x8*>(Bs + row * 128 + cb);
        }
#pragma unroll
        for (int mi = 0; mi < 4; ++mi)
#pragma unroll
            for (int ni = 0; ni < 4; ++ni)
                acc[mi][ni] = __builtin_amdgcn_mfma_f32_16x16x32_bf16(
                    af[mi], bf[ni], acc[mi][ni], 0, 0, 0);
    }
}

template <int MODE, int K>
__global__ __launch_bounds__(256) void gemm_fused(
    const unsigned short* __restrict__ Abase,  // mode0: activations; else emb_bf16
    const unsigned short* __restrict__ gvec,   // global embedding bf16 [256]
    const int* __restrict__ idx,               // clause node indices
    const unsigned short* __restrict__ WT,     // [N x K] bf16
    const float* __restrict__ bias,            // [N] fp32
    unsigned short* __restrict__ H,            // out [M x N] bf16
    int N) {
    __shared__ alignas(16) char smem[32768];
    char* As = smem;
    char* Bs = smem + 16384;

    const int t = threadIdx.x;
    const int w = t >> 6, lane = t & 63;
    const int bn = blockIdx.x, bm = blockIdx.y;
    const int wm = w >> 1, wn = w & 1;

    // staging geometry: round r covers 16B at linear offset o = w*1024 + lane*16 + r*4096
    int stg_row[4], stg_cs[4];
#pragma unroll
    for (int r = 0; r < 4; ++r) {
        int o = w * 1024 + lane * 16 + r * 4096;
        int row = o >> 7;
        int cphys = o & 127;
        stg_row[r] = row;
        stg_cs[r] = cphys ^ ((row & 7) << 4);  // pre-swizzled source column (involution)
    }

    const char* bsrc[4];
#pragma unroll
    for (int r = 0; r < 4; ++r) {
        int gn = bn * 128 + stg_row[r];
        bsrc[r] = (const char*)WT + (size_t)gn * K * 2 + stg_cs[r];
    }

    fx4 acc[4][4];
#pragma unroll
    for (int i = 0; i < 4; ++i)
#pragma unroll
        for (int j = 0; j < 4; ++j) acc[i][j] = {0.f, 0.f, 0.f, 0.f};

    if constexpr (MODE == 0) {
        const char* apre[4];
#pragma unroll
        for (int r = 0; r < 4; ++r) {
            int gm = bm * 128 + stg_row[r];
            apre[r] = (const char*)Abase + (size_t)gm * K * 2 + stg_cs[r];
        }
        constexpr int KSTEPS = K / 64;
        for (int kb = 0; kb < KSTEPS; ++kb) {
#pragma unroll
            for (int r = 0; r < 4; ++r) {
                __builtin_amdgcn_global_load_lds((AS1 void*)(apre[r] + kb * 128),
                                                 (AS3 void*)(As + w * 1024 + r * 4096),
                                                 16, 0, 0);
                __builtin_amdgcn_global_load_lds((AS1 void*)(bsrc[r] + kb * 128),
                                                 (AS3 void*)(Bs + w * 1024 + r * 4096),
                                                 16, 0, 0);
            }
            __syncthreads();
            compute64(As, Bs, acc, lane, wm, wn);
            __syncthreads();
        }
    } else {
        constexpr int NODES = (MODE == 1) ? 2 : 3;
        for (int seg = 0; seg < NODES + 1; ++seg) {
            const char* sp[4];
#pragma unroll
            for (int r = 0; r < 4; ++r) {
                int gm = bm * 128 + stg_row[r];
                const char* base;
                if (seg < NODES) {
                    int node = idx[(size_t)gm * NODES + seg];
                    base = (const char*)Abase + (size_t)node * 512;  // 256 bf16 per row
                } else {
                    base = (const char*)gvec;
                }
                sp[r] = base + stg_cs[r];
            }
            for (int kb2 = 0; kb2 < 4; ++kb2) {
                int kb = seg * 4 + kb2;
#pragma unroll
                for (int r = 0; r < 4; ++r) {
                    __builtin_amdgcn_global_load_lds((AS1 void*)(sp[r] + kb2 * 128),
                                                     (AS3 void*)(As + w * 1024 + r * 4096),
                                                     16, 0, 0);
                    __builtin_amdgcn_global_load_lds((AS1 void*)(bsrc[r] + kb * 128),
                                                     (AS3 void*)(Bs + w * 1024 + r * 4096),
                                                     16, 0, 0);
                }
                __syncthreads();
                compute64(As, Bs, acc, lane, wm, wn);
                __syncthreads();
            }
        }
    }

    // epilogue: bias + ReLU + bf16 store
#pragma unroll
    for (int mi = 0; mi < 4; ++mi) {
#pragma unroll
        for (int ni = 0; ni < 4; ++ni) {
            int gcol = bn * 128 + wn * 64 + ni * 16 + (lane & 15);
            float bv = bias[gcol];
            int grow0 = bm * 128 + wm * 64 + mi * 16 + ((lane >> 4) << 2);
            fx4 a = acc[mi][ni];
#pragma unroll
            for (int j = 0; j < 4; ++j) {
                float v = fmaxf(a[j] + bv, 0.f);
                H[(size_t)(grow0 + j) * N + gcol] = f2bf(v);
            }
        }
    }
}

// ---------------- final 256->1 dot ----------------
__global__ __launch_bounds__(256) void reduce_l4(const unsigned short* __restrict__ h3,
                                                 const float* __restrict__ Wc2,
                                                 const float* __restrict__ bc2,
                                                 float* __restrict__ out) {
    int w = threadIdx.x >> 6, lane = threadIdx.x & 63;
    int row = blockIdx.x * 4 + w;
    ushort4 v = *reinterpret_cast<const ushort4*>(h3 + (size_t)row * 256 + lane * 4);
    float4 wc = reinterpret_cast<const float4*>(Wc2)[lane];
    float s = bf2f(v.x) * wc.x + bf2f(v.y) * wc.y + bf2f(v.z) * wc.z + bf2f(v.w) * wc.w;
#pragma unroll
    for (int off = 32; off > 0; off >>= 1) s += __shfl_xor(s, off, 64);
    if (lane == 0) out[row] = s + bc2[0];
}

// ---------------- launch ----------------
extern "C" void kernel_launch(void* const* d_in, const int* in_sizes, int n_in,
                              void* d_out, int out_size, void* d_ws, size_t ws_size,
                              hipStream_t stream) {
    const float* local_emb  = (const float*)d_in[0];
    const float* global_emb = (const float*)d_in[1];
    const int* unary_idx    = (const int*)d_in[2];
    const int* binary_idx   = (const int*)d_in[3];
    const float* Wb1 = (const float*)d_in[4];
    const float* bb1 = (const float*)d_in[5];
    const float* Wb2 = (const float*)d_in[6];
    const float* bb2 = (const float*)d_in[7];
    const float* Wt1 = (const float*)d_in[8];
    const float* bt1 = (const float*)d_in[9];
    const float* Wt2 = (const float*)d_in[10];
    const float* bt2 = (const float*)d_in[11];
    const float* Wc1 = (const float*)d_in[12];
    const float* bc1 = (const float*)d_in[13];
    const float* Wc2 = (const float*)d_in[14];
    const float* bc2 = (const float*)d_in[15];
    float* out = (float*)d_out;

    constexpr int Hd = 256, U = 65536, B = 65536;
    const int NN = in_sizes[0] / Hd;  // num nodes

    char* ws = (char*)d_ws;
    size_t off = 0;
    auto alloc = [&](size_t bytes) {
        char* p = ws + off;
        off += (bytes + 255) & ~(size_t)255;
        return p;
    };
    unsigned short* emb_bf = (unsigned short*)alloc((size_t)NN * Hd * 2);
    unsigned short* g_bf   = (unsigned short*)alloc(Hd * 2);
    unsigned short* W1uT   = (unsigned short*)alloc(512 * 768 * 2);
    unsigned short* W2uT   = (unsigned short*)alloc(256 * 512 * 2);
    unsigned short* W1bT   = (unsigned short*)alloc(512 * 1024 * 2);
    unsigned short* W2bT   = (unsigned short*)alloc(256 * 512 * 2);
    unsigned short* Wc1T   = (unsigned short*)alloc(256 * 256 * 2);
    unsigned short* h1     = (unsigned short*)alloc((size_t)U * 512 * 2);
    unsigned short* h2     = (unsigned short*)alloc((size_t)U * 256 * 2);
    unsigned short* h3     = (unsigned short*)alloc((size_t)U * 256 * 2);

    // conversions (weights transposed to [N][K])
    int n4 = NN * Hd / 4;
    conv4<<<(n4 + 255) / 256, 256, 0, stream>>>(local_emb, emb_bf, n4);
    conv4<<<1, 64, 0, stream>>>(global_emb, g_bf, Hd / 4);
    convT<<<(512 * 768 + 255) / 256, 256, 0, stream>>>(Wb1, W1uT, 768, 512);
    convT<<<(256 * 512 + 255) / 256, 256, 0, stream>>>(Wb2, W2uT, 512, 256);
    convT<<<(512 * 1024 + 255) / 256, 256, 0, stream>>>(Wt1, W1bT, 1024, 512);
    convT<<<(256 * 512 + 255) / 256, 256, 0, stream>>>(Wt2, W2bT, 512, 256);
    convT<<<(256 * 256 + 255) / 256, 256, 0, stream>>>(Wc1, Wc1T, 256, 256);

    dim3 blk(256);
    // unary branch
    gemm_fused<1, 768><<<dim3(4, U / 128), blk, 0, stream>>>(emb_bf, g_bf, unary_idx, W1uT, bb1, h1, 512);
    gemm_fused<0, 512><<<dim3(2, U / 128), blk, 0, stream>>>(h1, nullptr, nullptr, W2uT, bb2, h2, 256);
    gemm_fused<0, 256><<<dim3(2, U / 128), blk, 0, stream>>>(h2, nullptr, nullptr, Wc1T, bc1, h3, 256);
    reduce_l4<<<U / 4, 256, 0, stream>>>(h3, Wc2, bc2, out);
    // binary branch (reuses h1/h2/h3)
    gemm_fused<2, 1024><<<dim3(4, B / 128), blk, 0, stream>>>(emb_bf, g_bf, binary_idx, W1bT, bt1, h1, 512);
    gemm_fused<0, 512><<<dim3(2, B / 128), blk, 0, stream>>>(h1, nullptr, nullptr, W2bT, bt2, h2, 256);
    gemm_fused<0, 256><<<dim3(2, B / 128), blk, 0, stream>>>(h2, nullptr, nullptr, Wc1T, bc1, h3, 256);
    reduce_l4<<<B / 4, 256, 0, stream>>>(h3, Wc2, bc2, out + U);

    (void)n_in; (void)out_size; (void)ws_size;
}

// Round 2
// 324.989 us; speedup vs baseline: 1.0558x; 1.0558x over previous
//
#include <hip/hip_runtime.h>
#include <cstdint>
#include <cstddef>

typedef __attribute__((ext_vector_type(8))) short s16x8;   // 8 x bf16 bits
typedef __attribute__((ext_vector_type(4))) float fx4;     // MFMA accumulator

#define AS1 __attribute__((address_space(1)))
#define AS3 __attribute__((address_space(3)))

__device__ __forceinline__ unsigned short f2bf(float f) {
    union { float f; unsigned u; } c; c.f = f;
    unsigned lsb = (c.u >> 16) & 1u;
    unsigned r = c.u + 0x7fffu + lsb;
    return (unsigned short)(r >> 16);
}
__device__ __forceinline__ float bf2f(unsigned short h) {
    union { unsigned u; float f; } c; c.u = ((unsigned)h) << 16;
    return c.f;
}

// ---------------- conversion kernels ----------------
__global__ __launch_bounds__(256) void conv4(const float* __restrict__ src,
                                             unsigned short* __restrict__ dst, int n4) {
    int i = blockIdx.x * 256 + threadIdx.x;
    if (i >= n4) return;
    float4 v = reinterpret_cast<const float4*>(src)[i];
    ushort4 o;
    o.x = f2bf(v.x); o.y = f2bf(v.y); o.z = f2bf(v.z); o.w = f2bf(v.w);
    reinterpret_cast<ushort4*>(dst)[i] = o;
}

// W [K x N] fp32 -> WT [N x K] bf16
__global__ __launch_bounds__(256) void convT(const float* __restrict__ W,
                                             unsigned short* __restrict__ WT, int K, int N) {
    int i = blockIdx.x * 256 + threadIdx.x;
    if (i >= N * K) return;
    int n = i / K, k = i - n * K;
    WT[i] = f2bf(W[(size_t)k * N + n]);
}

// ---------------- 8-wave pipelined fused GEMM ----------------
// C[m][n] = ReLU( sum_k A[m][k]*W[k][n] + bias[n] ) stored bf16 (stride N).
// BM=256, BN=128, BK=64. 8 waves = 4(M) x 2(N), wave tile 64x64.
// LDS: ring of 3 slots x (Ah0 16KB | Ah1 16KB | B 16KB) = 144KB.
// Pipeline: during K-tile kt, stage K-tile kt+2; counted vmcnt(6) per K-tile.
// MODE 0: A = Abase [M x K] bf16 contiguous.
// MODE 1: A row = concat(emb[idx[r*2+0..1]], gvec)      (K=768,  NSEG=3)
// MODE 2: A row = concat(emb[idx[r*3+0..2]], gvec)      (K=1024, NSEG=4)
template <int MODE, int K, int NSEG>
__global__ __launch_bounds__(512, 2) void gemm8(
    const unsigned short* __restrict__ Abase,
    const unsigned short* __restrict__ gvec,
    const int* __restrict__ idx,
    const unsigned short* __restrict__ WT,
    const float* __restrict__ bias,
    unsigned short* __restrict__ Hout,
    int N, int nbn) {
    __shared__ alignas(16) char smem_c[147456];
    constexpr int KT = K / 64;
    constexpr int NODES = NSEG - 1;

    const int t = threadIdx.x;
    const int w = t >> 6, lane = t & 63;
    const int wm = w >> 1, wn = w & 1;  // 4 x 2 wave grid

    // XCD-chunked bijective swizzle (nwg % 8 == 0 for all launches), bn-fastest.
    const int nwg = gridDim.x;
    const int o = blockIdx.x;
    const int q = nwg >> 3;
    const int widx = (o & 7) * q + (o >> 3);
    const int bn = widx % nbn, bm = widx / nbn;

    // ---- staging geometry ----
    // Wave-uniform dst + HW lane*16: granule r of wave w covers LDS
    // offset w*2048 + r*1024 + lane*16 -> (row = 16w + 8r + (lane>>3), col16 = lane&7).
    const int srow = (w << 4) + (lane >> 3);                  // row-in-half, r=0
    const int scs = ((lane & 7) ^ (lane >> 3)) << 4;          // pre-swizzled src col byte

    // B bases (rows of WT = output cols), scs folded in
    const char* bB0 = (const char*)WT + (size_t)(bn * 128 + srow) * (size_t)(K * 2) + scs;
    const char* bB1 = (const char*)WT + (size_t)(bn * 128 + srow + 8) * (size_t)(K * 2) + scs;

    // A bases per (half h, granule r)
    const char *A00 = nullptr, *A01 = nullptr, *A10 = nullptr, *A11 = nullptr;      // MODE0
    const char *g00a = nullptr, *g00b = nullptr, *g00c = nullptr, *g00d = nullptr;  // gather h0 r0
    const char *g01a = nullptr, *g01b = nullptr, *g01c = nullptr, *g01d = nullptr;  // h0 r1
    const char *g10a = nullptr, *g10b = nullptr, *g10c = nullptr, *g10d = nullptr;  // h1 r0
    const char *g11a = nullptr, *g11b = nullptr, *g11c = nullptr, *g11d = nullptr;  // h1 r1

    if constexpr (MODE == 0) {
        A00 = (const char*)Abase + (size_t)(bm * 256 + srow) * (size_t)(K * 2) + scs;
        A01 = (const char*)Abase + (size_t)(bm * 256 + srow + 8) * (size_t)(K * 2) + scs;
        A10 = (const char*)Abase + (size_t)(bm * 256 + 128 + srow) * (size_t)(K * 2) + scs;
        A11 = (const char*)Abase + (size_t)(bm * 256 + 128 + srow + 8) * (size_t)(K * 2) + scs;
    } else {
        const char* gv = (const char*)gvec + scs;
        auto nb = [&](int gm, int s) -> const char* {
            return (const char*)Abase + (size_t)idx[(size_t)gm * NODES + s] * 512 + scs;
        };
        int gm00 = bm * 256 + srow, gm01 = gm00 + 8;
        int gm10 = gm00 + 128, gm11 = gm01 + 128;
        g00a = nb(gm00, 0); g01a = nb(gm01, 0); g10a = nb(gm10, 0); g11a = nb(gm11, 0);
        if constexpr (NODES >= 2) { g00b = nb(gm00, 1); g01b = nb(gm01, 1); g10b = nb(gm10, 1); g11b = nb(gm11, 1); }
        if constexpr (NODES >= 3) { g00c = nb(gm00, 2); g01c = nb(gm01, 2); g10c = nb(gm10, 2); g11c = nb(gm11, 2); }
        if constexpr (NSEG == 2)      { g00b = gv; g01b = gv; g10b = gv; g11b = gv; }
        else if constexpr (NSEG == 3) { g00c = gv; g01c = gv; g10c = gv; g11c = gv; }
        else                          { g00d = gv; g01d = gv; g10d = gv; g11d = gv; }
    }

    auto segsel = [&](const char* pa, const char* pb, const char* pc, const char* pd,
                      int s) -> const char* {
        const char* r = pa;
        if constexpr (NSEG > 1) { if (s == 1) r = pb; }
        if constexpr (NSEG > 2) { if (s == 2) r = pc; }
        if constexpr (NSEG > 3) { if (s == 3) r = pd; }
        return r;
    };

#define GLL(src, dst) __builtin_amdgcn_global_load_lds((AS1 void*)(src), (AS3 void*)(dst), 16, 0, 0)

    auto stageA0 = [&](int kt2) {
        char* d = smem_c + (kt2 % 3) * 49152 + (w << 11);
        const char *s0, *s1;
        if constexpr (MODE == 0) {
            s0 = A00 + kt2 * 128; s1 = A01 + kt2 * 128;
        } else {
            int sg = kt2 >> 2, k4 = (kt2 & 3) * 128;
            s0 = segsel(g00a, g00b, g00c, g00d, sg) + k4;
            s1 = segsel(g01a, g01b, g01c, g01d, sg) + k4;
        }
        GLL(s0, d); GLL(s1, d + 1024);
    };
    auto stageA1 = [&](int kt2) {
        char* d = smem_c + (kt2 % 3) * 49152 + 16384 + (w << 11);
        const char *s0, *s1;
        if constexpr (MODE == 0) {
            s0 = A10 + kt2 * 128; s1 = A11 + kt2 * 128;
        } else {
            int sg = kt2 >> 2, k4 = (kt2 & 3) * 128;
            s0 = segsel(g10a, g10b, g10c, g10d, sg) + k4;
            s1 = segsel(g11a, g11b, g11c, g11d, sg) + k4;
        }
        GLL(s0, d); GLL(s1, d + 1024);
    };
    auto stageB = [&](int kt2) {
        char* d = smem_c + (kt2 % 3) * 49152 + 32768 + (w << 11);
        GLL(bB0 + kt2 * 128, d); GLL(bB1 + kt2 * 128, d + 1024);
    };

    // ---- fragment-read geometry ----
    const int ar = ((wm & 1) << 6) + (lane & 15);  // row-in-A-half (+ mi*16)
    const int br = (wn << 6) + (lane & 15);        // row-in-B-half (+ ni*16)
    const int hi = (lane >> 4) << 4;
    const int xl = (lane & 7) << 4;

    fx4 acc[4][4];
#pragma unroll
    for (int i = 0; i < 4; ++i)
#pragma unroll
        for (int j = 0; j < 4; ++j) acc[i][j] = {0.f, 0.f, 0.f, 0.f};

    // ---- prologue: stage K-tiles 0 and 1 ----
    stageA0(0); stageA1(0); stageB(0);
    stageA0(1); stageA1(1); stageB(1);
    asm volatile("s_waitcnt vmcnt(6)" ::: "memory");  // K-tile 0 landed (6 newer in flight)
    __builtin_amdgcn_s_barrier();

    s16x8 a[4], b[4];
    for (int kt = 0; kt < KT; ++kt) {
        const char* tb = smem_c + (kt % 3) * 49152;
        const char* Ah = tb + ((wm >> 1) << 14);
        const char* Bh = tb + 32768;
        const bool more = (kt + 2 < KT);

        // ---- phase 0: A(ks0) + B n0,n1 (ks0); stage Ah0(kt+2); MFMA n0,n1 ----
#pragma unroll
        for (int mi = 0; mi < 4; ++mi)
            a[mi] = *(const s16x8*)(Ah + (size_t)(ar + mi * 16) * 128 + (hi ^ xl));
        b[0] = *(const s16x8*)(Bh + (size_t)(br +  0) * 128 + (hi ^ xl));
        b[1] = *(const s16x8*)(Bh + (size_t)(br + 16) * 128 + (hi ^ xl));
        if (more) stageA0(kt + 2);
        __builtin_amdgcn_s_barrier();
        asm volatile("s_waitcnt lgkmcnt(0)" ::: "memory");
        __builtin_amdgcn_sched_barrier(0);
        __builtin_amdgcn_s_setprio(1);
#pragma unroll
        for (int mi = 0; mi < 4; ++mi) {
            acc[mi][0] = __builtin_amdgcn_mfma_f32_16x16x32_bf16(a[mi], b[0], acc[mi][0], 0, 0, 0);
            acc[mi][1] = __builtin_amdgcn_mfma_f32_16x16x32_bf16(a[mi], b[1], acc[mi][1], 0, 0, 0);
        }
        __builtin_amdgcn_s_setprio(0);
        __builtin_amdgcn_s_barrier();

        // ---- phase 1: B n2,n3 (ks0); stage Ah1(kt+2); MFMA n2,n3 ----
        b[2] = *(const s16x8*)(Bh + (size_t)(br + 32) * 128 + (hi ^ xl));
        b[3] = *(const s16x8*)(Bh + (size_t)(br + 48) * 128 + (hi ^ xl));
        if (more) stageA1(kt + 2);
        __builtin_amdgcn_s_barrier();
        asm volatile("s_waitcnt lgkmcnt(0)" ::: "memory");
        __builtin_amdgcn_sched_barrier(0);
        __builtin_amdgcn_s_setprio(1);
#pragma unroll
        for (int mi = 0; mi < 4; ++mi) {
            acc[mi][2] = __builtin_amdgcn_mfma_f32_16x16x32_bf16(a[mi], b[2], acc[mi][2], 0, 0, 0);
            acc[mi][3] = __builtin_amdgcn_mfma_f32_16x16x32_bf16(a[mi], b[3], acc[mi][3], 0, 0, 0);
        }
        __builtin_amdgcn_s_setprio(0);
        __builtin_amdgcn_s_barrier();

        // ---- phase 2: A(ks1) + B n0,n1 (ks1); stage B(kt+2); MFMA n0,n1 ----
#pragma unroll
        for (int mi = 0; mi < 4; ++mi)
            a[mi] = *(const s16x8*)(Ah + (size_t)(ar + mi * 16) * 128 + ((64 + hi) ^ xl));
        b[0] = *(const s16x8*)(Bh + (size_t)(br +  0) * 128 + ((64 + hi) ^ xl));
        b[1] = *(const s16x8*)(Bh + (size_t)(br + 16) * 128 + ((64 + hi) ^ xl));
        if (more) stageB(kt + 2);
        __builtin_amdgcn_s_barrier();
        asm volatile("s_waitcnt lgkmcnt(0)" ::: "memory");
        __builtin_amdgcn_sched_barrier(0);
        __builtin_amdgcn_s_setprio(1);
#pragma unroll
        for (int mi = 0; mi < 4; ++mi) {
            acc[mi][0] = __builtin_amdgcn_mfma_f32_16x16x32_bf16(a[mi], b[0], acc[mi][0], 0, 0, 0);
            acc[mi][1] = __builtin_amdgcn_mfma_f32_16x16x32_bf16(a[mi], b[1], acc[mi][1], 0, 0, 0);
        }
        __builtin_amdgcn_s_setprio(0);
        __builtin_amdgcn_s_barrier();

        // ---- phase 3: B n2,n3 (ks1); MFMA n2,n3; counted vmcnt; barrier ----
        b[2] = *(const s16x8*)(Bh + (size_t)(br + 32) * 128 + ((64 + hi) ^ xl));
        b[3] = *(const s16x8*)(Bh + (size_t)(br + 48) * 128 + ((64 + hi) ^ xl));
        __builtin_amdgcn_s_barrier();
        asm volatile("s_waitcnt lgkmcnt(0)" ::: "memory");
        __builtin_amdgcn_sched_barrier(0);
        __builtin_amdgcn_s_setprio(1);
#pragma unroll
        for (int mi = 0; mi < 4; ++mi) {
            acc[mi][2] = __builtin_amdgcn_mfma_f32_16x16x32_bf16(a[mi], b[2], acc[mi][2], 0, 0, 0);
            acc[mi][3] = __builtin_amdgcn_mfma_f32_16x16x32_bf16(a[mi], b[3], acc[mi][3], 0, 0, 0);
        }
        __builtin_amdgcn_s_setprio(0);
        if (more) { asm volatile("s_waitcnt vmcnt(6)" ::: "memory"); }
        else      { asm volatile("s_waitcnt vmcnt(0)" ::: "memory"); }
        __builtin_amdgcn_s_barrier();
    }
#undef GLL

    // ---- epilogue: bias + ReLU + bf16 store ----
#pragma unroll
    for (int mi = 0; mi < 4; ++mi) {
#pragma unroll
        for (int ni = 0; ni < 4; ++ni) {
            int gcol = bn * 128 + wn * 64 + ni * 16 + (lane & 15);
            float bv = bias[gcol];
            int grow0 = bm * 256 + wm * 64 + mi * 16 + ((lane >> 4) << 2);
            fx4 v = acc[mi][ni];
#pragma unroll
            for (int j = 0; j < 4; ++j) {
                float x = fmaxf(v[j] + bv, 0.f);
                Hout[(size_t)(grow0 + j) * N + gcol] = f2bf(x);
            }
        }
    }
}

// ---------------- final 256->1 dot ----------------
__global__ __launch_bounds__(256) void reduce_l4(const unsigned short* __restrict__ h3,
                                                 const float* __restrict__ Wc2,
                                                 const float* __restrict__ bc2,
                                                 float* __restrict__ out) {
    int w = threadIdx.x >> 6, lane = threadIdx.x & 63;
    int row = blockIdx.x * 4 + w;
    ushort4 v = *reinterpret_cast<const ushort4*>(h3 + (size_t)row * 256 + lane * 4);
    float4 wc = reinterpret_cast<const float4*>(Wc2)[lane];
    float s = bf2f(v.x) * wc.x + bf2f(v.y) * wc.y + bf2f(v.z) * wc.z + bf2f(v.w) * wc.w;
#pragma unroll
    for (int off = 32; off > 0; off >>= 1) s += __shfl_xor(s, off, 64);
    if (lane == 0) out[row] = s + bc2[0];
}

// ---------------- launch ----------------
extern "C" void kernel_launch(void* const* d_in, const int* in_sizes, int n_in,
                              void* d_out, int out_size, void* d_ws, size_t ws_size,
                              hipStream_t stream) {
    const float* local_emb  = (const float*)d_in[0];
    const float* global_emb = (const float*)d_in[1];
    const int* unary_idx    = (const int*)d_in[2];
    const int* binary_idx   = (const int*)d_in[3];
    const float* Wb1 = (const float*)d_in[4];
    const float* bb1 = (const float*)d_in[5];
    const float* Wb2 = (const float*)d_in[6];
    const float* bb2 = (const float*)d_in[7];
    const float* Wt1 = (const float*)d_in[8];
    const float* bt1 = (const float*)d_in[9];
    const float* Wt2 = (const float*)d_in[10];
    const float* bt2 = (const float*)d_in[11];
    const float* Wc1 = (const float*)d_in[12];
    const float* bc1 = (const float*)d_in[13];
    const float* Wc2 = (const float*)d_in[14];
    const float* bc2 = (const float*)d_in[15];
    float* out = (float*)d_out;

    constexpr int Hd = 256, U = 65536, B = 65536;
    const int NN = in_sizes[0] / Hd;

    char* ws = (char*)d_ws;
    size_t off = 0;
    auto alloc = [&](size_t bytes) {
        char* p = ws + off;
        off += (bytes + 255) & ~(size_t)255;
        return p;
    };
    unsigned short* emb_bf = (unsigned short*)alloc((size_t)NN * Hd * 2);
    unsigned short* g_bf   = (unsigned short*)alloc(Hd * 2);
    unsigned short* W1uT   = (unsigned short*)alloc(512 * 768 * 2);
    unsigned short* W2uT   = (unsigned short*)alloc(256 * 512 * 2);
    unsigned short* W1bT   = (unsigned short*)alloc(512 * 1024 * 2);
    unsigned short* W2bT   = (unsigned short*)alloc(256 * 512 * 2);
    unsigned short* Wc1T   = (unsigned short*)alloc(256 * 256 * 2);
    unsigned short* h1     = (unsigned short*)alloc((size_t)U * 512 * 2);
    unsigned short* h2     = (unsigned short*)alloc((size_t)U * 256 * 2);
    unsigned short* h3     = (unsigned short*)alloc((size_t)U * 256 * 2);

    int n4 = NN * Hd / 4;
    conv4<<<(n4 + 255) / 256, 256, 0, stream>>>(local_emb, emb_bf, n4);
    conv4<<<1, 64, 0, stream>>>(global_emb, g_bf, Hd / 4);
    convT<<<(512 * 768 + 255) / 256, 256, 0, stream>>>(Wb1, W1uT, 768, 512);
    convT<<<(256 * 512 + 255) / 256, 256, 0, stream>>>(Wb2, W2uT, 512, 256);
    convT<<<(512 * 1024 + 255) / 256, 256, 0, stream>>>(Wt1, W1bT, 1024, 512);
    convT<<<(256 * 512 + 255) / 256, 256, 0, stream>>>(Wt2, W2bT, 512, 256);
    convT<<<(256 * 256 + 255) / 256, 256, 0, stream>>>(Wc1, Wc1T, 256, 256);

    dim3 blk(512);
    // unary branch
    gemm8<1, 768, 3><<<dim3(1024), blk, 0, stream>>>(emb_bf, g_bf, unary_idx, W1uT, bb1, h1, 512, 4);
    gemm8<0, 512, 1><<<dim3(512), blk, 0, stream>>>(h1, nullptr, nullptr, W2uT, bb2, h2, 256, 2);
    gemm8<0, 256, 1><<<dim3(512), blk, 0, stream>>>(h2, nullptr, nullptr, Wc1T, bc1, h3, 256, 2);
    reduce_l4<<<U / 4, 256, 0, stream>>>(h3, Wc2, bc2, out);
    // binary branch (reuses h1/h2/h3)
    gemm8<2, 1024, 4><<<dim3(1024), blk, 0, stream>>>(emb_bf, g_bf, binary_idx, W1bT, bt1, h1, 512, 4);
    gemm8<0, 512, 1><<<dim3(512), blk, 0, stream>>>(h1, nullptr, nullptr, W2bT, bt2, h2, 256, 2);
    gemm8<0, 256, 1><<<dim3(512), blk, 0, stream>>>(h2, nullptr, nullptr, Wc1T, bc1, h3, 256, 2);
    reduce_l4<<<B / 4, 256, 0, stream>>>(h3, Wc2, bc2, out + U);

    (void)n_in; (void)out_size; (void)ws_size;
}

// Round 3
// 262.321 us; speedup vs baseline: 1.3080x; 1.2389x over previous
//
#include <hip/hip_runtime.h>
#include <cstdint>
#include <cstddef>

typedef __attribute__((ext_vector_type(8))) short s16x8;   // 8 x bf16 bits
typedef __attribute__((ext_vector_type(4))) float fx4;     // MFMA accumulator

#define AS1 __attribute__((address_space(1)))
#define AS3 __attribute__((address_space(3)))

__device__ __forceinline__ unsigned short f2bf(float f) {
    union { float f; unsigned u; } c; c.f = f;
    unsigned lsb = (c.u >> 16) & 1u;
    unsigned r = c.u + 0x7fffu + lsb;
    return (unsigned short)(r >> 16);
}
__device__ __forceinline__ float bf2f(unsigned short h) {
    union { unsigned u; float f; } c; c.u = ((unsigned)h) << 16;
    return c.f;
}

// ---------------- conversion kernels ----------------
__global__ __launch_bounds__(256) void conv4(const float* __restrict__ src,
                                             unsigned short* __restrict__ dst, int n4) {
    int i = blockIdx.x * 256 + threadIdx.x;
    if (i >= n4) return;
    float4 v = reinterpret_cast<const float4*>(src)[i];
    ushort4 o;
    o.x = f2bf(v.x); o.y = f2bf(v.y); o.z = f2bf(v.z); o.w = f2bf(v.w);
    reinterpret_cast<ushort4*>(dst)[i] = o;
}

// W [K x N] fp32 -> WT [N x K] bf16
__global__ __launch_bounds__(256) void convT(const float* __restrict__ W,
                                             unsigned short* __restrict__ WT, int K, int N) {
    int i = blockIdx.x * 256 + threadIdx.x;
    if (i >= N * K) return;
    int n = i / K, k = i - n * K;
    WT[i] = f2bf(W[(size_t)k * N + n]);
}

// ---------------- m201-style 8-phase 256x256 fused GEMM ----------------
// C = ReLU(A @ W + bias), A gathered (MODE 1/2) or dense (MODE 0).
// BM=256, BN=256, BK=64; 8 waves = 2(M) x 4(N), wave tile 128x64.
// LDS: 2 buffers x (A 32KB | B 32KB) = 128KB (+4KB reduce scratch).
// 2 K-tiles per iteration, 8 phases; even tiles -> buf0, odd -> buf1.
// Stage schedule (half-tiles, 2 GLL each):
//   ph1: t+1.A1  ph2: t+1.B0  ph3: t+1.B1  ph4: t+2.A0  (vmcnt(2))
//   ph5: t+2.A1  ph6: t+2.B0  ph7: t+2.B1  ph8: t+3.A0  (vmcnt(2))
// FOUT: fuse final 256->1 dot (Wc2, bc2) into the epilogue, write fp32 out.
template <int MODE, int K, int NSEG, bool FOUT>
__global__ __launch_bounds__(512, 2) void gemm256(
    const unsigned short* __restrict__ Abase,
    const unsigned short* __restrict__ gvec,
    const int* __restrict__ idx,
    const unsigned short* __restrict__ WT,
    const float* __restrict__ bias,
    unsigned short* __restrict__ Hout,
    float* __restrict__ outF,
    const float* __restrict__ Wc2,
    const float* __restrict__ bc2,
    int N, int nbn) {
    __shared__ alignas(16) char smem_c[131072 + 4096];
    constexpr int KT = K / 64;
    constexpr int NODES = NSEG - 1;
    constexpr int NODESZ = (MODE == 0) ? 1 : NODES;

    const int t = threadIdx.x;
    const int w = t >> 6, lane = t & 63;
    const int wm = w >> 2, wn = w & 3;  // 2M x 4N waves

    // XCD-chunked bijective swizzle (grid % 8 == 0 in all launches), bn-fastest
    const int nwg = gridDim.x, o = blockIdx.x, q = nwg >> 3;
    const int widx = (o & 7) * q + (o >> 3);
    const int bn = widx % nbn, bm = widx / nbn;

    // staging geometry: granule r of wave w -> LDS rows w*8 + (lane>>3) + r*64
    const int l3 = lane >> 3, l7 = lane & 7, l15 = lane & 15;
    const int scs = (l7 ^ l3) << 4;  // pre-swizzled source col (involution)

    const char* Abc = (const char*)Abase;
    const char* Gvc = (const char*)gvec;
    const char* WTc = (const char*)WT;

    uint32_t boff[2][2];
    uint32_t aoff[2][2][NODESZ];
#pragma unroll
    for (int h = 0; h < 2; ++h)
#pragma unroll
        for (int r = 0; r < 2; ++r) {
            int srow = h * 128 + w * 8 + l3 + r * 64;
            boff[h][r] = (uint32_t)(bn * 256 + srow) * (uint32_t)(K * 2) + scs;
            int gm = bm * 256 + srow;
            if constexpr (MODE == 0) {
                aoff[h][r][0] = (uint32_t)gm * (uint32_t)(K * 2) + scs;
            } else {
#pragma unroll
                for (int s = 0; s < NODES; ++s)
                    aoff[h][r][s] = (uint32_t)idx[(size_t)gm * NODES + s] * 512u + scs;
            }
        }

#define GLL(src, dst) __builtin_amdgcn_global_load_lds((AS1 void*)(src), (AS3 void*)(dst), 16, 0, 0)

#define STAGE_A(hh, tsrc, pb) do { \
    char* d_ = smem_c + (pb) * 65536 + (hh) * 16384 + (w << 10); \
    if constexpr (MODE == 0) { \
        GLL(Abc + aoff[hh][0][0] + (tsrc) * 128, d_); \
        GLL(Abc + aoff[hh][1][0] + (tsrc) * 128, d_ + 8192); \
    } else { \
        int seg_ = (tsrc) >> 2, k4_ = ((tsrc) & 3) << 7; \
        if (seg_ < NODES) { \
            uint32_t v0_ = aoff[hh][0][0], v1_ = aoff[hh][1][0]; \
            if constexpr (NODESZ >= 2) { if (seg_ >= 1) { v0_ = aoff[hh][0][1]; v1_ = aoff[hh][1][1]; } } \
            if constexpr (NODESZ >= 3) { if (seg_ >= 2) { v0_ = aoff[hh][0][2]; v1_ = aoff[hh][1][2]; } } \
            GLL(Abc + v0_ + k4_, d_); GLL(Abc + v1_ + k4_, d_ + 8192); \
        } else { \
            const char* s_ = Gvc + scs + k4_; \
            GLL(s_, d_); GLL(s_, d_ + 8192); \
        } \
    } \
} while (0)

#define STAGE_B(hh, tsrc, pb) do { \
    char* d_ = smem_c + (pb) * 65536 + 32768 + (hh) * 16384 + (w << 10); \
    GLL(WTc + boff[hh][0] + (tsrc) * 128, d_); \
    GLL(WTc + boff[hh][1] + (tsrc) * 128, d_ + 8192); \
} while (0)

    // fragment-read geometry
    const int armul = wm * 16384 + l15 * 128;          // A: row base (within buf)
    const int brmul = 32768 + wn * 8192 + l15 * 128;   // B: row base (within buf)
    const int hi = (lane >> 4) << 4, xl = l7 << 4;
    const int c0 = hi ^ xl, c1 = (64 + hi) ^ xl;

#define READ_A(mh, pb) do { \
    const char* base_ = smem_c + (pb) * 65536 + armul; \
    _Pragma("unroll") for (int r_ = 0; r_ < 4; ++r_) { \
        a[r_ * 2 + 0] = *(const s16x8*)(base_ + ((mh) * 4 + r_) * 2048 + c0); \
        a[r_ * 2 + 1] = *(const s16x8*)(base_ + ((mh) * 4 + r_) * 2048 + c1); \
    } \
} while (0)

#define READ_B(nh, pb, BARR) do { \
    const char* base_ = smem_c + (pb) * 65536 + brmul; \
    _Pragma("unroll") for (int c_ = 0; c_ < 2; ++c_) { \
        BARR[c_ * 2 + 0] = *(const s16x8*)(base_ + ((nh) * 2 + c_) * 2048 + c0); \
        BARR[c_ * 2 + 1] = *(const s16x8*)(base_ + ((nh) * 2 + c_) * 2048 + c1); \
    } \
} while (0)

#define MFMA16(mh, nh, BARR) do { \
    _Pragma("unroll") for (int ks_ = 0; ks_ < 2; ++ks_) \
    _Pragma("unroll") for (int r_ = 0; r_ < 4; ++r_) \
    _Pragma("unroll") for (int c_ = 0; c_ < 2; ++c_) \
        acc[(mh) * 4 + r_][(nh) * 2 + c_] = __builtin_amdgcn_mfma_f32_16x16x32_bf16( \
            a[r_ * 2 + ks_], BARR[c_ * 2 + ks_], acc[(mh) * 4 + r_][(nh) * 2 + c_], 0, 0, 0); \
} while (0)

#define SYNC_PRE() do { \
    __builtin_amdgcn_s_barrier(); \
    asm volatile("s_waitcnt lgkmcnt(0)" ::: "memory"); \
    __builtin_amdgcn_sched_barrier(0); \
    __builtin_amdgcn_s_setprio(1); \
} while (0)

    fx4 acc[8][4];
#pragma unroll
    for (int i = 0; i < 8; ++i)
#pragma unroll
        for (int j = 0; j < 4; ++j) acc[i][j] = {0.f, 0.f, 0.f, 0.f};

    // ---- prologue: tile 0 full + tile 1 A0 ----
    STAGE_A(0, 0, 0); STAGE_A(1, 0, 0); STAGE_B(0, 0, 0); STAGE_B(1, 0, 0);
    STAGE_A(0, 1, 1);
    asm volatile("s_waitcnt vmcnt(2)" ::: "memory");
    __builtin_amdgcn_s_barrier();

    s16x8 a[8], bl[4], bh[4];
    for (int tt = 0; tt < KT; tt += 2) {
        const int t1 = tt + 1;
        const int t2c = (tt + 2 < KT) ? tt + 2 : KT - 1;
        const int t3c = (tt + 3 < KT) ? tt + 3 : KT - 1;

        // ---- tile tt (buf0) ----
        READ_A(0, 0); READ_B(0, 0, bl);
        STAGE_A(1, t1, 1);
        SYNC_PRE(); MFMA16(0, 0, bl); __builtin_amdgcn_s_setprio(0);
        __builtin_amdgcn_s_barrier();

        READ_B(1, 0, bh);
        STAGE_B(0, t1, 1);
        SYNC_PRE(); MFMA16(0, 1, bh); __builtin_amdgcn_s_setprio(0);
        __builtin_amdgcn_s_barrier();

        READ_A(1, 0);
        STAGE_B(1, t1, 1);
        SYNC_PRE(); MFMA16(1, 0, bl); __builtin_amdgcn_s_setprio(0);
        __builtin_amdgcn_s_barrier();

        STAGE_A(0, t2c, 0);
        SYNC_PRE(); MFMA16(1, 1, bh); __builtin_amdgcn_s_setprio(0);
        asm volatile("s_waitcnt vmcnt(2)" ::: "memory");
        __builtin_amdgcn_s_barrier();

        // ---- tile tt+1 (buf1) ----
        READ_A(0, 1); READ_B(0, 1, bl);
        STAGE_A(1, t2c, 0);
        SYNC_PRE(); MFMA16(0, 0, bl); __builtin_amdgcn_s_setprio(0);
        __builtin_amdgcn_s_barrier();

        READ_B(1, 1, bh);
        STAGE_B(0, t2c, 0);
        SYNC_PRE(); MFMA16(0, 1, bh); __builtin_amdgcn_s_setprio(0);
        __builtin_amdgcn_s_barrier();

        READ_A(1, 1);
        STAGE_B(1, t2c, 0);
        SYNC_PRE(); MFMA16(1, 0, bl); __builtin_amdgcn_s_setprio(0);
        __builtin_amdgcn_s_barrier();

        STAGE_A(0, t3c, 1);
        SYNC_PRE(); MFMA16(1, 1, bh); __builtin_amdgcn_s_setprio(0);
        asm volatile("s_waitcnt vmcnt(2)" ::: "memory");
        __builtin_amdgcn_s_barrier();
    }
    asm volatile("s_waitcnt vmcnt(0)" ::: "memory");

#undef GLL
#undef STAGE_A
#undef STAGE_B
#undef READ_A
#undef READ_B
#undef MFMA16
#undef SYNC_PRE

    const int hi2 = (lane >> 4);  // 0..3

    if constexpr (FOUT) {
        // fused: out[row] = sum_c relu(h[row][c] + bias[c]) * Wc2[c] + bc2
        float* part = (float*)(smem_c + 131072);
        float bv[4], wv[4];
#pragma unroll
        for (int ni = 0; ni < 4; ++ni) {
            int gcol = wn * 64 + ni * 16 + l15;
            bv[ni] = bias[gcol];
            wv[ni] = Wc2[gcol];
        }
#pragma unroll
        for (int mi = 0; mi < 8; ++mi) {
#pragma unroll
            for (int j = 0; j < 4; ++j) {
                float s = 0.f;
#pragma unroll
                for (int ni = 0; ni < 4; ++ni)
                    s += fmaxf(acc[mi][ni][j] + bv[ni], 0.f) * wv[ni];
                s += __shfl_xor(s, 1); s += __shfl_xor(s, 2);
                s += __shfl_xor(s, 4); s += __shfl_xor(s, 8);
                if (l15 == 0) {
                    int row = wm * 128 + mi * 16 + hi2 * 4 + j;
                    part[row * 4 + wn] = s;
                }
            }
        }
        __syncthreads();
        if (t < 256) {
            float o2 = part[t * 4] + part[t * 4 + 1] + part[t * 4 + 2] + part[t * 4 + 3] + bc2[0];
            outF[bm * 256 + t] = o2;
        }
    } else {
#pragma unroll
        for (int mi = 0; mi < 8; ++mi) {
#pragma unroll
            for (int ni = 0; ni < 4; ++ni) {
                int gcol = bn * 256 + wn * 64 + ni * 16 + l15;
                float bvv = bias[gcol];
                int grow0 = bm * 256 + wm * 128 + mi * 16 + hi2 * 4;
                fx4 v = acc[mi][ni];
#pragma unroll
                for (int j = 0; j < 4; ++j) {
                    float x = fmaxf(v[j] + bvv, 0.f);
                    Hout[(size_t)(grow0 + j) * N + gcol] = f2bf(x);
                }
            }
        }
    }
}

// ---------------- launch ----------------
extern "C" void kernel_launch(void* const* d_in, const int* in_sizes, int n_in,
                              void* d_out, int out_size, void* d_ws, size_t ws_size,
                              hipStream_t stream) {
    const float* local_emb  = (const float*)d_in[0];
    const float* global_emb = (const float*)d_in[1];
    const int* unary_idx    = (const int*)d_in[2];
    const int* binary_idx   = (const int*)d_in[3];
    const float* Wb1 = (const float*)d_in[4];
    const float* bb1 = (const float*)d_in[5];
    const float* Wb2 = (const float*)d_in[6];
    const float* bb2 = (const float*)d_in[7];
    const float* Wt1 = (const float*)d_in[8];
    const float* bt1 = (const float*)d_in[9];
    const float* Wt2 = (const float*)d_in[10];
    const float* bt2 = (const float*)d_in[11];
    const float* Wc1 = (const float*)d_in[12];
    const float* bc1 = (const float*)d_in[13];
    const float* Wc2 = (const float*)d_in[14];
    const float* bc2 = (const float*)d_in[15];
    float* out = (float*)d_out;

    constexpr int Hd = 256, U = 65536, B = 65536;
    const int NN = in_sizes[0] / Hd;

    char* ws = (char*)d_ws;
    size_t off = 0;
    auto alloc = [&](size_t bytes) {
        char* p = ws + off;
        off += (bytes + 255) & ~(size_t)255;
        return p;
    };
    unsigned short* emb_bf = (unsigned short*)alloc((size_t)NN * Hd * 2);
    unsigned short* g_bf   = (unsigned short*)alloc(Hd * 2);
    unsigned short* W1uT   = (unsigned short*)alloc(512 * 768 * 2);
    unsigned short* W2uT   = (unsigned short*)alloc(256 * 512 * 2);
    unsigned short* W1bT   = (unsigned short*)alloc(512 * 1024 * 2);
    unsigned short* W2bT   = (unsigned short*)alloc(256 * 512 * 2);
    unsigned short* Wc1T   = (unsigned short*)alloc(256 * 256 * 2);
    unsigned short* h1     = (unsigned short*)alloc((size_t)U * 512 * 2);
    unsigned short* h2     = (unsigned short*)alloc((size_t)U * 256 * 2);

    int n4 = NN * Hd / 4;
    conv4<<<(n4 + 255) / 256, 256, 0, stream>>>(local_emb, emb_bf, n4);
    conv4<<<1, 64, 0, stream>>>(global_emb, g_bf, Hd / 4);
    convT<<<(512 * 768 + 255) / 256, 256, 0, stream>>>(Wb1, W1uT, 768, 512);
    convT<<<(256 * 512 + 255) / 256, 256, 0, stream>>>(Wb2, W2uT, 512, 256);
    convT<<<(512 * 1024 + 255) / 256, 256, 0, stream>>>(Wt1, W1bT, 1024, 512);
    convT<<<(256 * 512 + 255) / 256, 256, 0, stream>>>(Wt2, W2bT, 512, 256);
    convT<<<(256 * 256 + 255) / 256, 256, 0, stream>>>(Wc1, Wc1T, 256, 256);

    dim3 blk(512);
    // unary branch
    gemm256<1, 768, 3, false><<<dim3(512), blk, 0, stream>>>(
        emb_bf, g_bf, unary_idx, W1uT, bb1, h1, nullptr, nullptr, nullptr, 512, 2);
    gemm256<0, 512, 1, false><<<dim3(256), blk, 0, stream>>>(
        h1, nullptr, nullptr, W2uT, bb2, h2, nullptr, nullptr, nullptr, 256, 1);
    gemm256<0, 256, 1, true><<<dim3(256), blk, 0, stream>>>(
        h2, nullptr, nullptr, Wc1T, bc1, nullptr, out, Wc2, bc2, 256, 1);
    // binary branch (reuses h1/h2)
    gemm256<2, 1024, 4, false><<<dim3(512), blk, 0, stream>>>(
        emb_bf, g_bf, binary_idx, W1bT, bt1, h1, nullptr, nullptr, nullptr, 512, 2);
    gemm256<0, 512, 1, false><<<dim3(256), blk, 0, stream>>>(
        h1, nullptr, nullptr, W2bT, bt2, h2, nullptr, nullptr, nullptr, 256, 1);
    gemm256<0, 256, 1, true><<<dim3(256), blk, 0, stream>>>(
        h2, nullptr, nullptr, Wc1T, bc1, nullptr, out + U, Wc2, bc2, 256, 1);

    (void)n_in; (void)out_size; (void)ws_size;
}